// Round 6
// baseline (457.275 us; speedup 1.0000x reference)
//
#include <hip/hip_runtime.h>
#include <stdint.h>

#define C      1024
#define NH     16
#define HS     64
#define CT     65536
#define PAST   61440   // CT - WINDOW
#define KEEP   12288   // MIN_KV - WINDOW
#define NCOMP  192     // KEEP/64
#define NSEL   32
#define NB     8192    // selection bins

typedef unsigned long long ull;

// monotone transform: larger float => smaller u (asc u == desc value)
__device__ __forceinline__ unsigned int desc_key(float f) {
    unsigned int b = __float_as_uint(f);
    return (b >> 31) ? b : (~b & 0x7FFFFFFFu);
}
__device__ __forceinline__ float u_to_f(unsigned int u) {
    unsigned int b = (u & 0x80000000u) ? u : (0x7FFFFFFFu - u);
    return __uint_as_float(b);
}
// monotone linear bin: s descending <-> bin ascending
__device__ __forceinline__ int bin_of(float s, float hi, float scale) {
    int b = (int)((hi - s) * scale);
    return b < 0 ? 0 : (b > NB - 1 ? NB - 1 : b);
}
__device__ __forceinline__ void load_params(const unsigned* umin, const unsigned* umax,
                                            int h, float* hi, float* sc) {
    float h2 = u_to_f(umin[h]);
    float lo = u_to_f(umax[h]);
    float r = h2 - lo;
    *hi = h2;
    *sc = (r > 0.f) ? (float)(NB - 1) / r : 0.f;
}

// ---------------- K1: q/k/v projections + all zero-inits ---------------------
__global__ void k_proj(const float* __restrict__ x, const float* __restrict__ Wr,
                       const float* __restrict__ Wk, const float* __restrict__ Wv,
                       float* __restrict__ q, float* __restrict__ kn, float* __restrict__ vn,
                       unsigned* __restrict__ hist, unsigned* __restrict__ umin,
                       unsigned* __restrict__ umax, ull* __restrict__ cs_fix,
                       unsigned* __restrict__ bar) {
    int id = blockIdx.x * 256 + threadIdx.x;
    if (id < NH * NB) hist[id] = 0;
    if (blockIdx.x == 699 && threadIdx.x < 8) bar[threadIdx.x] = 0u;
    if (blockIdx.x == 700) {
        if (threadIdx.x < 16) umin[threadIdx.x] = 0xFFFFFFFFu;
        else if (threadIdx.x < 32) umax[threadIdx.x - 16] = 0u;
    }
    if (blockIdx.x == 701 && threadIdx.x < 256) cs_fix[threadIdx.x] = 0ull;

    int w = blockIdx.x * (blockDim.x >> 6) + (threadIdx.x >> 6); // 0..3071
    int lane = threadIdx.x & 63;
    int mat = w >> 10, row = w & 1023;
    const float* W = (mat == 0) ? Wr : (mat == 1) ? Wk : Wv;
    const float4* Wrow = (const float4*)(W + (size_t)row * C);
    const float4* x4 = (const float4*)x;
    float acc = 0.f;
#pragma unroll
    for (int i = 0; i < 4; ++i) {
        float4 a = Wrow[i * 64 + lane];
        float4 b = x4[i * 64 + lane];
        acc += a.x * b.x + a.y * b.y + a.z * b.z + a.w * b.w;
    }
#pragma unroll
    for (int off = 32; off; off >>= 1) acc += __shfl_xor(acc, off);
    if (lane == 0) { (mat == 0 ? q : (mat == 1 ? kn : vn))[row] = acc; }
}

// ---- K2: scores (64 chunk-aligned tokens/block) + minmax + window sums ------
__global__ __launch_bounds__(512) void k_scores(const float* __restrict__ kc,
                         const float* __restrict__ q, float* __restrict__ s,
                         unsigned* __restrict__ umin, unsigned* __restrict__ umax,
                         ull* __restrict__ cs_fix) {
    __shared__ float sc_l[8][16][8];
    const int tid = threadIdx.x;
    const int wave = tid >> 6, lane = tid & 63;
    const int T0 = blockIdx.x * 64;
    const int t0 = T0 + wave * 8;
    const float4* q4 = (const float4*)q;
    float4 qv[4];
#pragma unroll
    for (int i = 0; i < 4; ++i) qv[i] = q4[i * 64 + lane];
    for (int tt = 0; tt < 8; ++tt) {
        const float4* row = (const float4*)(kc + (size_t)(t0 + tt) * C);
        float acc[4];
#pragma unroll
        for (int i = 0; i < 4; ++i) {
            float4 a = row[i * 64 + lane];
            acc[i] = a.x * qv[i].x + a.y * qv[i].y + a.z * qv[i].z + a.w * qv[i].w;
        }
#pragma unroll
        for (int off = 8; off; off >>= 1) {
#pragma unroll
            for (int i = 0; i < 4; ++i) acc[i] += __shfl_xor(acc[i], off);
        }
        if ((lane & 15) == 0) {
            int g = lane >> 4;
#pragma unroll
            for (int i = 0; i < 4; ++i) sc_l[wave][4 * i + g][tt] = acc[i];
        }
    }
    __syncthreads();
    // write phase: 32 threads per head, 2 consecutive tokens each (256B/head)
    const int h = tid >> 5, toff = (tid & 31) * 2;
    float v0 = sc_l[toff >> 3][h][toff & 7];
    float v1 = sc_l[toff >> 3][h][(toff & 7) + 1];
    s[(size_t)h * CT + T0 + toff] = v0;
    s[(size_t)h * CT + T0 + toff + 1] = v1;
    if (blockIdx.x < 960) {                    // PAST region: min/max
        float mn = fminf(v0, v1), mx = fmaxf(v0, v1);
#pragma unroll
        for (int off = 16; off; off >>= 1) {
            mn = fminf(mn, __shfl_xor(mn, off));
            mx = fmaxf(mx, __shfl_xor(mx, off));
        }
        if ((tid & 31) == 0) {
            atomicMin(&umin[h], desc_key(mx));
            atomicMax(&umax[h], desc_key(mn));
        }
    } else {                                   // window region: chunk sums
        long long f = llrintf(v0 * 16777216.f) + llrintf(v1 * 16777216.f);
#pragma unroll
        for (int off = 16; off; off >>= 1) f += __shfl_xor(f, off);
        if ((tid & 31) == 0)
            atomicAdd(&cs_fix[NCOMP + (blockIdx.x - 960)], (ull)f);
    }
}

// ------- S1: histogram (4 blocks/head) + last-block scan & threshold ---------
__global__ __launch_bounds__(1024) void s1_hist(const float* __restrict__ s,
                                                unsigned* __restrict__ base,
                                                const unsigned* __restrict__ umin,
                                                const unsigned* __restrict__ umax,
                                                unsigned* __restrict__ Tarr,
                                                unsigned* __restrict__ bar) {
    __shared__ unsigned lh[NB];
    __shared__ unsigned sh_last;
    const int tid = threadIdx.x;
    const int lane = tid & 63, wave = tid >> 6;
    {
        int h = blockIdx.x >> 2, seg = blockIdx.x & 3;
        for (int i = tid; i < NB; i += 1024) lh[i] = 0;
        __syncthreads();
        float hi, sc; load_params(umin, umax, h, &hi, &sc);
        const float* sh = s + (size_t)h * CT + seg * 15360;
        for (int i = tid; i < 15360; i += 1024)
            atomicAdd(&lh[bin_of(sh[i], hi, sc)], 1u);
        __syncthreads();
        unsigned* gh = base + h * NB;
        for (int i = tid; i < NB; i += 1024) {
            unsigned c = lh[i];
            if (c) atomicAdd(&gh[i], c);
        }
    }
    // last arriving block scans all heads (wave w = head w)
    __threadfence();
    if (tid == 0) sh_last = (atomicAdd(&bar[0], 1u) == 63u) ? 1u : 0u;
    __syncthreads();
    if (!sh_last) return;
    __threadfence();
    {
        unsigned* B = base + wave * NB;
        int b0 = lane * 128;
        unsigned lsum = 0;
        for (int k = 0; k < 128; ++k) lsum += B[b0 + k];
        unsigned run = lsum;
#pragma unroll
        for (int off = 1; off < 64; off <<= 1) {
            unsigned n = __shfl_up(run, off);
            if (lane >= off) run += n;
        }
        unsigned r = run - lsum;               // exclusive prefix
        for (int k = 0; k < 128; ++k) {
            unsigned c = B[b0 + k];
            B[b0 + k] = r;
            unsigned inc = r + c;
            if (r < KEEP && inc >= KEEP) Tarr[wave] = (unsigned)(b0 + k);
            r = inc;
        }
    }
}

// ---------------- S3: scatter candidates (bins <= T) into G ------------------
__global__ __launch_bounds__(1024) void s3_scatter(const float* __restrict__ s,
                                                   unsigned* __restrict__ base,
                                                   const unsigned* __restrict__ Tarr,
                                                   ull* __restrict__ G,
                                                   const unsigned* __restrict__ umin,
                                                   const unsigned* __restrict__ umax) {
    int h = blockIdx.x / 60, seg = blockIdx.x % 60;
    int t = seg * 1024 + threadIdx.x;   // < 61440
    float hi, sc; load_params(umin, umax, h, &hi, &sc);
    float v = s[(size_t)h * CT + t];
    int b = bin_of(v, hi, sc);
    if ((unsigned)b <= Tarr[h]) {
        unsigned pos = atomicAdd(&base[h * NB + b], 1u);
        G[(size_t)h * 65536 + pos] = ((ull)desc_key(v) << 16) | (unsigned)t;
    }
}

// ---- S4: exact rank; emit stok + chunk sums; last block does top-32 ---------
__global__ __launch_bounds__(1024) void s4_rank(const unsigned* __restrict__ base,
                                                const unsigned* __restrict__ Tarr,
                                                const ull* __restrict__ G,
                                                const unsigned* __restrict__ umin,
                                                const unsigned* __restrict__ umax,
                                                unsigned short* __restrict__ stok,
                                                ull* __restrict__ cs_fix,
                                                unsigned* __restrict__ sel,
                                                unsigned* __restrict__ bar) {
    __shared__ ull csl[NCOMP];
    __shared__ unsigned sh_last;
    __shared__ ull key[256];
    const int tid = threadIdx.x;
    {
        if (tid < NCOMP) csl[tid] = 0ull;
        __syncthreads();
        int h = blockIdx.x >> 4, seg = blockIdx.x & 15;
        float hi, sc; load_params(umin, umax, h, &hi, &sc);
        unsigned T = Tarr[h];
        unsigned ncand = base[h * NB + T];
        const ull* Gh = G + (size_t)h * 65536;
        for (unsigned p = seg * 1024 + tid; p < ncand; p += 16384) {
            ull pk = Gh[p];
            unsigned u = (unsigned)(pk >> 16);
            float v = u_to_f(u);
            int b = bin_of(v, hi, sc);
            unsigned start = b ? base[h * NB + b - 1] : 0u;
            unsigned end = base[h * NB + b];
            unsigned rank = start;
            for (unsigned j = start; j < end; ++j) rank += (Gh[j] < pk) ? 1u : 0u;
            if (rank < KEEP) {
                stok[h * KEEP + rank] = (unsigned short)(pk & 0xFFFFull);
                long long f = llrintf(v * 16777216.f);
                atomicAdd(&csl[rank >> 6], (ull)f);
            }
        }
        __syncthreads();
        if (tid < NCOMP) {
            ull c = csl[tid];
            if (c) atomicAdd(&cs_fix[tid], c);
        }
    }
    // last arriving block: top-32 chunks via bitonic sort of 256
    __threadfence();
    if (tid == 0) sh_last = (atomicAdd(&bar[1], 1u) == 255u) ? 1u : 0u;
    __syncthreads();
    if (!sh_last) return;
    __threadfence();
    if (tid < 256) {
        long long v = (long long)cs_fix[tid];
        ull bb = (ull)(v + (1ll << 45));                     // strictly positive
        key[tid] = (((1ull << 46) - bb) << 8) | (unsigned)tid; // asc == (val desc, idx asc)
    }
    __syncthreads();
    for (unsigned k = 2; k <= 256; k <<= 1) {
        for (unsigned j = k >> 1; j > 0; j >>= 1) {
            if (tid < 256) {
                unsigned ixj = tid ^ j;
                if (ixj > (unsigned)tid) {
                    ull a = key[tid], b = key[ixj];
                    bool up = ((tid & k) == 0);
                    if (up ? (a > b) : (a < b)) { key[tid] = b; key[ixj] = a; }
                }
            }
            __syncthreads();
        }
    }
    if (tid < NSEL) sel[tid] = (unsigned)(key[tid] & 0xFFull);
}

// ---------------- K5a: per (head, selected chunk) partial softmax+PV ---------
__global__ void k_attn_part(const float* __restrict__ s, const float* __restrict__ vc,
                            const unsigned short* __restrict__ stok,
                            const unsigned int* __restrict__ sel,
                            float* __restrict__ part) {
    int h = blockIdx.x >> 5, ci = blockIdx.x & 31;
    int tid = threadIdx.x;     // 256
    int g = tid >> 2, b3 = tid & 3;
    int c = (int)sel[ci];
    int t = (c < NCOMP) ? (int)stok[h * KEEP + c * 64 + g]
                        : (PAST + (c - NCOMP) * 64 + g);
    __shared__ float scm[64];
    __shared__ float ex[64];
    __shared__ float vbuf[64][65];
    if (b3 == 0) scm[g] = s[(size_t)h * CT + t] * 0.125f;
    __syncthreads();
    float m = -1e30f;
    for (int j = 0; j < 64; ++j) m = fmaxf(m, scm[j]);
    float e = expf(scm[g] - m);
    const float4* vrow = (const float4*)(vc + (size_t)t * C + h * HS);
#pragma unroll
    for (int it = 0; it < 4; ++it) {
        float4 vv = vrow[it * 4 + b3];
        int d0 = it * 16 + b3 * 4;
        vbuf[g][d0 + 0] = e * vv.x;
        vbuf[g][d0 + 1] = e * vv.y;
        vbuf[g][d0 + 2] = e * vv.z;
        vbuf[g][d0 + 3] = e * vv.w;
    }
    if (b3 == 0) ex[g] = e;
    __syncthreads();
    if (tid < 64) {
        float acc = 0.f;
        for (int g2 = 0; g2 < 64; ++g2) acc += vbuf[g2][tid];
        float* P = part + (size_t)(h * 32 + ci) * 68;
        P[2 + tid] = acc;
        if (tid == 0) {
            float es = 0.f;
            for (int g2 = 0; g2 < 64; ++g2) es += ex[g2];
            P[0] = m;
            P[1] = es;
        }
    }
}

// ------- K6: combine partials -> y (LDS, redundant per block) -> out ---------
__global__ __launch_bounds__(1024) void k_finout(const float* __restrict__ part,
        const float* __restrict__ q, const float* __restrict__ kn,
        const float* __restrict__ vn, const float* __restrict__ Wo,
        float* __restrict__ out) {
    __shared__ float yl[1024];
    __shared__ float qdl[16];
    const int tid = threadIdx.x, wave = tid >> 6, lane = tid & 63;
    {
        float p = q[wave * 64 + lane] * kn[wave * 64 + lane];
#pragma unroll
        for (int off = 32; off; off >>= 1) p += __shfl_xor(p, off);
        if (lane == 0) qdl[wave] = p;
    }
    __syncthreads();
    {
        float a_new = qdl[wave] * 0.125f;
        const float* P0 = part + (size_t)wave * 32 * 68;
        float m = a_new;
        for (int ci = 0; ci < 32; ++ci) m = fmaxf(m, P0[ci * 68]);
        float den = expf(a_new - m);
        float acc = den * vn[wave * HS + lane];
        for (int ci = 0; ci < 32; ++ci) {
            float w = expf(P0[ci * 68] - m);
            den += w * P0[ci * 68 + 1];
            acc += w * P0[ci * 68 + 2 + lane];
        }
        yl[tid] = acc / den;
    }
    __syncthreads();
    int r = blockIdx.x * 16 + wave;            // 0..1023
    const float4* Wrow = (const float4*)(Wo + (size_t)r * C);
    const float4* y4 = (const float4*)yl;
    float acc = 0.f;
#pragma unroll
    for (int i = 0; i < 4; ++i) {
        float4 a = Wrow[i * 64 + lane];
        float4 b = y4[i * 64 + lane];
        acc += a.x * b.x + a.y * b.y + a.z * b.z + a.w * b.w;
    }
#pragma unroll
    for (int off = 32; off; off >>= 1) acc += __shfl_xor(acc, off);
    if (lane == 0) out[r] = acc;
}

extern "C" void kernel_launch(void* const* d_in, const int* in_sizes, int n_in,
                              void* d_out, int out_size, void* d_ws, size_t ws_size,
                              hipStream_t stream) {
    const float* x  = (const float*)d_in[0];
    const float* kc = (const float*)d_in[1];
    const float* vc = (const float*)d_in[2];
    const float* Wr = (const float*)d_in[3];
    const float* Wk = (const float*)d_in[4];
    const float* Wv = (const float*)d_in[5];
    const float* Wo = (const float*)d_in[6];
    float* out = (float*)d_out;
    char* ws = (char*)d_ws;

    float* q    = (float*)(ws + 0);
    float* kn   = (float*)(ws + 8192);
    float* vn   = (float*)(ws + 16384);
    ull* cs_fix = (ull*)(ws + 32768);                         // 2 KiB
    unsigned* sel = (unsigned*)(ws + 40960);
    float* part = (float*)(ws + 49152);                       // 139264 B
    unsigned short* stok = (unsigned short*)(ws + 196608);    // 393216 B
    unsigned* umin = (unsigned*)(ws + 602112);
    unsigned* umax = (unsigned*)(ws + 602176);
    unsigned* Tarr = (unsigned*)(ws + 602240);
    unsigned* bar  = (unsigned*)(ws + 602368);                // 8 counters
    unsigned* base = (unsigned*)(ws + 655360);                // 512 KiB
    float* s = (float*)(ws + 2097152);                        // 4 MiB
    ull* G = (ull*)(ws + 6291456);                            // 8 MiB

    k_proj<<<768, 256, 0, stream>>>(x, Wr, Wk, Wv, q, kn, vn, base, umin, umax, cs_fix, bar);
    k_scores<<<1024, 512, 0, stream>>>(kc, q, s, umin, umax, cs_fix);
    s1_hist<<<64, 1024, 0, stream>>>(s, base, umin, umax, Tarr, bar);
    s3_scatter<<<960, 1024, 0, stream>>>(s, base, Tarr, G, umin, umax);
    s4_rank<<<256, 1024, 0, stream>>>(base, Tarr, G, umin, umax, stok, cs_fix, sel, bar);
    k_attn_part<<<512, 256, 0, stream>>>(s, vc, stok, sel, part);
    k_finout<<<64, 1024, 0, stream>>>(part, q, kn, vn, Wo, out);
}

// Round 7
// 326.511 us; speedup vs baseline: 1.4005x; 1.4005x over previous
//
#include <hip/hip_runtime.h>
#include <stdint.h>

#define C      1024
#define NH     16
#define HS     64
#define CT     65536
#define PAST   61440   // CT - WINDOW
#define KEEP   12288   // MIN_KV - WINDOW
#define NCOMP  192     // KEEP/64
#define NSEL   32
#define NB     8192    // selection bins

typedef unsigned long long ull;

// monotone transform: larger float => smaller u (asc u == desc value)
__device__ __forceinline__ unsigned int desc_key(float f) {
    unsigned int b = __float_as_uint(f);
    return (b >> 31) ? b : (~b & 0x7FFFFFFFu);
}
__device__ __forceinline__ float u_to_f(unsigned int u) {
    unsigned int b = (u & 0x80000000u) ? u : (0x7FFFFFFFu - u);
    return __uint_as_float(b);
}
// monotone linear bin: s descending <-> bin ascending
__device__ __forceinline__ int bin_of(float s, float hi, float scale) {
    int b = (int)((hi - s) * scale);
    return b < 0 ? 0 : (b > NB - 1 ? NB - 1 : b);
}
__device__ __forceinline__ void load_params(const unsigned* umin, const unsigned* umax,
                                            int h, float* hi, float* sc) {
    float h2 = u_to_f(umin[h]);
    float lo = u_to_f(umax[h]);
    float r = h2 - lo;
    *hi = h2;
    *sc = (r > 0.f) ? (float)(NB - 1) / r : 0.f;
}

// ---------------- K1: q/k/v projections + all zero-inits ---------------------
__global__ void k_proj(const float* __restrict__ x, const float* __restrict__ Wr,
                       const float* __restrict__ Wk, const float* __restrict__ Wv,
                       float* __restrict__ q, float* __restrict__ kn, float* __restrict__ vn,
                       unsigned* __restrict__ hist, unsigned* __restrict__ umin,
                       unsigned* __restrict__ umax, ull* __restrict__ cs_fix,
                       unsigned* __restrict__ bar) {
    int id = blockIdx.x * 256 + threadIdx.x;
    if (id < NH * NB) hist[id] = 0;
    if (blockIdx.x == 699 && threadIdx.x < 8) bar[threadIdx.x] = 0u;
    if (blockIdx.x == 700) {
        if (threadIdx.x < 16) umin[threadIdx.x] = 0xFFFFFFFFu;
        else if (threadIdx.x < 32) umax[threadIdx.x - 16] = 0u;
    }
    if (blockIdx.x == 701 && threadIdx.x < 256) cs_fix[threadIdx.x] = 0ull;

    int w = blockIdx.x * (blockDim.x >> 6) + (threadIdx.x >> 6); // 0..3071
    int lane = threadIdx.x & 63;
    int mat = w >> 10, row = w & 1023;
    const float* W = (mat == 0) ? Wr : (mat == 1) ? Wk : Wv;
    const float4* Wrow = (const float4*)(W + (size_t)row * C);
    const float4* x4 = (const float4*)x;
    float acc = 0.f;
#pragma unroll
    for (int i = 0; i < 4; ++i) {
        float4 a = Wrow[i * 64 + lane];
        float4 b = x4[i * 64 + lane];
        acc += a.x * b.x + a.y * b.y + a.z * b.z + a.w * b.w;
    }
#pragma unroll
    for (int off = 32; off; off >>= 1) acc += __shfl_xor(acc, off);
    if (lane == 0) { (mat == 0 ? q : (mat == 1 ? kn : vn))[row] = acc; }
}

// ------- K2: per-head raw scores s[h][t] = qh.k_cache[t,h]  (+minmax) --------
__global__ void k_scores(const float* __restrict__ kc, const float* __restrict__ q,
                         float* __restrict__ s, unsigned* __restrict__ umin,
                         unsigned* __restrict__ umax) {
    __shared__ float smn[4][16], smx[4][16];
    int wid = blockIdx.x * (blockDim.x >> 6) + (threadIdx.x >> 6);
    int lane = threadIdx.x & 63, wave = threadIdx.x >> 6;
    int nw = gridDim.x * (blockDim.x >> 6);
    const float4* q4 = (const float4*)q;
    float4 qv[4];
#pragma unroll
    for (int i = 0; i < 4; ++i) qv[i] = q4[i * 64 + lane];
    float mnv[4] = {3.4e38f, 3.4e38f, 3.4e38f, 3.4e38f};
    float mxv[4] = {-3.4e38f, -3.4e38f, -3.4e38f, -3.4e38f};
    for (int t = wid; t < CT; t += nw) {
        const float4* row = (const float4*)(kc + (size_t)t * C);
        float acc[4];
#pragma unroll
        for (int i = 0; i < 4; ++i) {
            float4 a = row[i * 64 + lane];
            acc[i] = a.x * qv[i].x + a.y * qv[i].y + a.z * qv[i].z + a.w * qv[i].w;
        }
#pragma unroll
        for (int off = 8; off; off >>= 1) {
#pragma unroll
            for (int i = 0; i < 4; ++i) acc[i] += __shfl_xor(acc[i], off);
        }
        if ((lane & 15) == 0) {
            int g = lane >> 4;
#pragma unroll
            for (int i = 0; i < 4; ++i) {
                s[(size_t)(4 * i + g) * CT + t] = acc[i];
                if (t < PAST) {
                    mnv[i] = fminf(mnv[i], acc[i]);
                    mxv[i] = fmaxf(mxv[i], acc[i]);
                }
            }
        }
    }
    if ((lane & 15) == 0) {
        int g = lane >> 4;
#pragma unroll
        for (int i = 0; i < 4; ++i) { smn[wave][4 * i + g] = mnv[i]; smx[wave][4 * i + g] = mxv[i]; }
    }
    __syncthreads();
    if (threadIdx.x < 16) {
        int h = threadIdx.x;
        float mn = smn[0][h], mx = smx[0][h];
        for (int w2 = 1; w2 < 4; ++w2) {
            mn = fminf(mn, smn[w2][h]);
            mx = fmaxf(mx, smx[w2][h]);
        }
        atomicMin(&umin[h], desc_key(mx));   // smallest key == largest value
        atomicMax(&umax[h], desc_key(mn));   // largest key == smallest value
    }
}

// -- S1: histogram (4 blocks/head); last block: parallel scan + threshold -----
__global__ __launch_bounds__(1024) void s1_hist(const float* __restrict__ s,
                                                unsigned* __restrict__ base,
                                                const unsigned* __restrict__ umin,
                                                const unsigned* __restrict__ umax,
                                                unsigned* __restrict__ Tarr,
                                                unsigned* __restrict__ bar) {
    __shared__ unsigned lh[NB];
    __shared__ unsigned sh_last;
    const int tid = threadIdx.x;
    const int lane = tid & 63, wave = tid >> 6;
    {
        int h = blockIdx.x >> 2, seg = blockIdx.x & 3;
        for (int i = tid; i < NB; i += 1024) lh[i] = 0;
        __syncthreads();
        float hi, sc; load_params(umin, umax, h, &hi, &sc);
        const float* sh = s + (size_t)h * CT + seg * 15360;
        for (int i = tid; i < 15360; i += 1024)
            atomicAdd(&lh[bin_of(sh[i], hi, sc)], 1u);
        __syncthreads();
        unsigned* gh = base + h * NB;
        for (int i = tid; i < NB; i += 1024) {
            unsigned c = lh[i];
            if (c) atomicAdd(&gh[i], c);
        }
    }
    // arrival (waves drained by syncthreads' vmcnt(0) before barrier)
    __syncthreads();
    if (tid == 0) sh_last = (atomicAdd(&bar[0], 1u) == 63u) ? 1u : 0u;
    __syncthreads();
    if (!sh_last) return;
    __threadfence();                         // acquire (single block only)
    __syncthreads();
    // parallel scan: wave w = head w; lane l owns bins [l*128, l*128+128)
    {
        unsigned* __restrict__ B = base + wave * NB;
        const int b0 = lane * 128;
        // pass A: streaming per-lane sum (independent loads)
        unsigned lsum = 0;
#pragma unroll 8
        for (int k = 0; k < 128; ++k) lsum += B[b0 + k];
        // wave-exclusive scan of lane sums
        unsigned run = lsum;
#pragma unroll
        for (int off = 1; off < 64; off <<= 1) {
            unsigned n = __shfl_up(run, off);
            if (lane >= off) run += n;
        }
        unsigned r = run - lsum;
        // pass B: L2-hot rewrite with exclusive bases + threshold detect
#pragma unroll 4
        for (int k = 0; k < 128; ++k) {
            unsigned c = B[b0 + k];
            B[b0 + k] = r;
            unsigned inc = r + c;
            if (r < KEEP && inc >= KEEP) Tarr[wave] = (unsigned)(b0 + k);
            r = inc;
        }
    }
}

// ---- S3: scatter candidates (bins <= T) into G; +16 window-sum blocks -------
__global__ __launch_bounds__(1024) void s3_scatter(const float* __restrict__ s,
                                                   unsigned* __restrict__ base,
                                                   const unsigned* __restrict__ Tarr,
                                                   ull* __restrict__ G,
                                                   const unsigned* __restrict__ umin,
                                                   const unsigned* __restrict__ umax,
                                                   ull* __restrict__ cs_fix) {
    if (blockIdx.x >= 960) {                 // window-chunk fixed-point sums
        int h = blockIdx.x - 960;
        int tid = threadIdx.x;
        int c = tid >> 4;                    // 16 threads per chunk
        const float* sh = s + (size_t)h * CT + PAST + tid * 4;
        long long f = llrintf(sh[0] * 16777216.f) + llrintf(sh[1] * 16777216.f)
                    + llrintf(sh[2] * 16777216.f) + llrintf(sh[3] * 16777216.f);
#pragma unroll
        for (int off = 8; off; off >>= 1) f += __shfl_xor(f, off);
        if ((tid & 15) == 0) atomicAdd(&cs_fix[NCOMP + c], (ull)f);
        return;
    }
    int h = blockIdx.x / 60, seg = blockIdx.x % 60;
    int t = seg * 1024 + threadIdx.x;   // < 61440
    float hi, sc; load_params(umin, umax, h, &hi, &sc);
    float v = s[(size_t)h * CT + t];
    int b = bin_of(v, hi, sc);
    if ((unsigned)b <= Tarr[h]) {
        unsigned pos = atomicAdd(&base[h * NB + b], 1u);
        G[(size_t)h * 65536 + pos] = ((ull)desc_key(v) << 16) | (unsigned)t;
    }
}

// ---- S4: exact rank; emit stok + chunk sums; last block: top-32 -------------
__global__ __launch_bounds__(1024) void s4_rank(const unsigned* __restrict__ base,
                                                const unsigned* __restrict__ Tarr,
                                                const ull* __restrict__ G,
                                                const unsigned* __restrict__ umin,
                                                const unsigned* __restrict__ umax,
                                                unsigned short* __restrict__ stok,
                                                ull* __restrict__ cs_fix,
                                                unsigned* __restrict__ sel,
                                                unsigned* __restrict__ bar) {
    __shared__ ull csl[NCOMP];
    __shared__ unsigned sh_last;
    __shared__ ull key[256];
    const int tid = threadIdx.x;
    {
        if (tid < NCOMP) csl[tid] = 0ull;
        __syncthreads();
        int h = blockIdx.x >> 4, seg = blockIdx.x & 15;
        float hi, sc; load_params(umin, umax, h, &hi, &sc);
        unsigned T = Tarr[h];
        unsigned ncand = base[h * NB + T];
        const ull* Gh = G + (size_t)h * 65536;
        for (unsigned p = seg * 1024 + tid; p < ncand; p += 16384) {
            ull pk = Gh[p];
            unsigned u = (unsigned)(pk >> 16);
            float v = u_to_f(u);
            int b = bin_of(v, hi, sc);
            unsigned start = b ? base[h * NB + b - 1] : 0u;
            unsigned end = base[h * NB + b];
            unsigned rank = start;
            for (unsigned j = start; j < end; ++j) rank += (Gh[j] < pk) ? 1u : 0u;
            if (rank < KEEP) {
                stok[h * KEEP + rank] = (unsigned short)(pk & 0xFFFFull);
                long long f = llrintf(v * 16777216.f);
                atomicAdd(&csl[rank >> 6], (ull)f);
            }
        }
        __syncthreads();
        if (tid < NCOMP) {
            ull c = csl[tid];
            if (c) atomicAdd(&cs_fix[tid], c);
        }
    }
    // arrival; last block computes top-32 (parallel bitonic in LDS)
    __syncthreads();
    if (tid == 0) sh_last = (atomicAdd(&bar[1], 1u) == 255u) ? 1u : 0u;
    __syncthreads();
    if (!sh_last) return;
    __threadfence();                         // acquire (single block only)
    __syncthreads();
    if (tid < 256) {
        long long v = (long long)cs_fix[tid];
        ull bb = (ull)(v + (1ll << 45));                       // strictly positive
        key[tid] = (((1ull << 46) - bb) << 8) | (unsigned)tid; // asc == (val desc, idx asc)
    }
    __syncthreads();
    for (unsigned k = 2; k <= 256; k <<= 1) {
        for (unsigned j = k >> 1; j > 0; j >>= 1) {
            if (tid < 256) {
                unsigned ixj = tid ^ j;
                if (ixj > (unsigned)tid) {
                    ull a = key[tid], b = key[ixj];
                    bool up = ((tid & k) == 0);
                    if (up ? (a > b) : (a < b)) { key[tid] = b; key[ixj] = a; }
                }
            }
            __syncthreads();
        }
    }
    if (tid < NSEL) sel[tid] = (unsigned)(key[tid] & 0xFFull);
}

// ---------------- K5a: per (head, selected chunk) partial softmax+PV ---------
__global__ void k_attn_part(const float* __restrict__ s, const float* __restrict__ vc,
                            const unsigned short* __restrict__ stok,
                            const unsigned int* __restrict__ sel,
                            float* __restrict__ part) {
    int h = blockIdx.x >> 5, ci = blockIdx.x & 31;
    int tid = threadIdx.x;     // 256
    int g = tid >> 2, b3 = tid & 3;
    int c = (int)sel[ci];
    int t = (c < NCOMP) ? (int)stok[h * KEEP + c * 64 + g]
                        : (PAST + (c - NCOMP) * 64 + g);
    __shared__ float scm[64];
    __shared__ float ex[64];
    __shared__ float vbuf[64][65];
    if (b3 == 0) scm[g] = s[(size_t)h * CT + t] * 0.125f;
    __syncthreads();
    float m = -1e30f;
    for (int j = 0; j < 64; ++j) m = fmaxf(m, scm[j]);
    float e = expf(scm[g] - m);
    const float4* vrow = (const float4*)(vc + (size_t)t * C + h * HS);
#pragma unroll
    for (int it = 0; it < 4; ++it) {
        float4 vv = vrow[it * 4 + b3];
        int d0 = it * 16 + b3 * 4;
        vbuf[g][d0 + 0] = e * vv.x;
        vbuf[g][d0 + 1] = e * vv.y;
        vbuf[g][d0 + 2] = e * vv.z;
        vbuf[g][d0 + 3] = e * vv.w;
    }
    if (b3 == 0) ex[g] = e;
    __syncthreads();
    if (tid < 64) {
        float acc = 0.f;
        for (int g2 = 0; g2 < 64; ++g2) acc += vbuf[g2][tid];
        float* P = part + (size_t)(h * 32 + ci) * 68;
        P[2 + tid] = acc;
        if (tid == 0) {
            float es = 0.f;
            for (int g2 = 0; g2 < 64; ++g2) es += ex[g2];
            P[0] = m;
            P[1] = es;
        }
    }
}

// ------- K6: combine partials -> y (LDS, redundant per block) -> out ---------
__global__ __launch_bounds__(1024) void k_finout(const float* __restrict__ part,
        const float* __restrict__ q, const float* __restrict__ kn,
        const float* __restrict__ vn, const float* __restrict__ Wo,
        float* __restrict__ out) {
    __shared__ float yl[1024];
    __shared__ float qdl[16];
    const int tid = threadIdx.x, wave = tid >> 6, lane = tid & 63;
    {
        float p = q[wave * 64 + lane] * kn[wave * 64 + lane];
#pragma unroll
        for (int off = 32; off; off >>= 1) p += __shfl_xor(p, off);
        if (lane == 0) qdl[wave] = p;
    }
    __syncthreads();
    {
        float a_new = qdl[wave] * 0.125f;
        const float* P0 = part + (size_t)wave * 32 * 68;
        float m = a_new;
        for (int ci = 0; ci < 32; ++ci) m = fmaxf(m, P0[ci * 68]);
        float den = expf(a_new - m);
        float acc = den * vn[wave * HS + lane];
        for (int ci = 0; ci < 32; ++ci) {
            float w = expf(P0[ci * 68] - m);
            den += w * P0[ci * 68 + 1];
            acc += w * P0[ci * 68 + 2 + lane];
        }
        yl[tid] = acc / den;
    }
    __syncthreads();
    int r = blockIdx.x * 16 + wave;            // 0..1023
    const float4* Wrow = (const float4*)(Wo + (size_t)r * C);
    const float4* y4 = (const float4*)yl;
    float acc = 0.f;
#pragma unroll
    for (int i = 0; i < 4; ++i) {
        float4 a = Wrow[i * 64 + lane];
        float4 b = y4[i * 64 + lane];
        acc += a.x * b.x + a.y * b.y + a.z * b.z + a.w * b.w;
    }
#pragma unroll
    for (int off = 32; off; off >>= 1) acc += __shfl_xor(acc, off);
    if (lane == 0) out[r] = acc;
}

extern "C" void kernel_launch(void* const* d_in, const int* in_sizes, int n_in,
                              void* d_out, int out_size, void* d_ws, size_t ws_size,
                              hipStream_t stream) {
    const float* x  = (const float*)d_in[0];
    const float* kc = (const float*)d_in[1];
    const float* vc = (const float*)d_in[2];
    const float* Wr = (const float*)d_in[3];
    const float* Wk = (const float*)d_in[4];
    const float* Wv = (const float*)d_in[5];
    const float* Wo = (const float*)d_in[6];
    float* out = (float*)d_out;
    char* ws = (char*)d_ws;

    float* q    = (float*)(ws + 0);
    float* kn   = (float*)(ws + 8192);
    float* vn   = (float*)(ws + 16384);
    ull* cs_fix = (ull*)(ws + 32768);                         // 2 KiB
    unsigned* sel = (unsigned*)(ws + 40960);
    float* part = (float*)(ws + 49152);                       // 139264 B
    unsigned short* stok = (unsigned short*)(ws + 196608);    // 393216 B
    unsigned* umin = (unsigned*)(ws + 602112);
    unsigned* umax = (unsigned*)(ws + 602176);
    unsigned* Tarr = (unsigned*)(ws + 602240);
    unsigned* bar  = (unsigned*)(ws + 602368);                // 8 counters
    unsigned* base = (unsigned*)(ws + 655360);                // 512 KiB
    float* s = (float*)(ws + 2097152);                        // 4 MiB
    ull* G = (ull*)(ws + 6291456);                            // 8 MiB

    k_proj<<<768, 256, 0, stream>>>(x, Wr, Wk, Wv, q, kn, vn, base, umin, umax, cs_fix, bar);
    k_scores<<<2048, 256, 0, stream>>>(kc, q, s, umin, umax);
    s1_hist<<<64, 1024, 0, stream>>>(s, base, umin, umax, Tarr, bar);
    s3_scatter<<<976, 1024, 0, stream>>>(s, base, Tarr, G, umin, umax, cs_fix);
    s4_rank<<<256, 1024, 0, stream>>>(base, Tarr, G, umin, umax, stok, cs_fix, sel, bar);
    k_attn_part<<<512, 256, 0, stream>>>(s, vc, stok, sel, part);
    k_finout<<<64, 1024, 0, stream>>>(part, q, kn, vn, Wo, out);
}

// Round 8
// 145.517 us; speedup vs baseline: 3.1424x; 2.2438x over previous
//
#include <hip/hip_runtime.h>
#include <stdint.h>

#define C      1024
#define NH     16
#define HS     64
#define CT     65536
#define PAST   61440   // CT - WINDOW
#define KEEP   12288   // MIN_KV - WINDOW
#define NCOMP  192     // KEEP/64
#define NSEL   32
#define NB     8192    // selection bins

typedef unsigned long long ull;

// monotone transform: larger float => smaller u (asc u == desc value)
__device__ __forceinline__ unsigned int desc_key(float f) {
    unsigned int b = __float_as_uint(f);
    return (b >> 31) ? b : (~b & 0x7FFFFFFFu);
}
__device__ __forceinline__ float u_to_f(unsigned int u) {
    unsigned int b = (u & 0x80000000u) ? u : (0x7FFFFFFFu - u);
    return __uint_as_float(b);
}
// monotone linear bin: s descending <-> bin ascending
__device__ __forceinline__ int bin_of(float s, float hi, float scale) {
    int b = (int)((hi - s) * scale);
    return b < 0 ? 0 : (b > NB - 1 ? NB - 1 : b);
}
__device__ __forceinline__ void load_params(const unsigned* umin, const unsigned* umax,
                                            int h, float* hi, float* sc) {
    float h2 = u_to_f(umin[h]);
    float lo = u_to_f(umax[h]);
    float r = h2 - lo;
    *hi = h2;
    *sc = (r > 0.f) ? (float)(NB - 1) / r : 0.f;
}

// ---------------- K1: q/k/v projections + all zero-inits ---------------------
__global__ void k_proj(const float* __restrict__ x, const float* __restrict__ Wr,
                       const float* __restrict__ Wk, const float* __restrict__ Wv,
                       float* __restrict__ q, float* __restrict__ kn, float* __restrict__ vn,
                       unsigned* __restrict__ hist, unsigned* __restrict__ umin,
                       unsigned* __restrict__ umax, ull* __restrict__ cs_fix,
                       unsigned* __restrict__ bar) {
    int id = blockIdx.x * 256 + threadIdx.x;
    if (id < NH * NB) hist[id] = 0;
    if (blockIdx.x == 699 && threadIdx.x < 8) bar[threadIdx.x] = 0u;
    if (blockIdx.x == 700) {
        if (threadIdx.x < 16) umin[threadIdx.x] = 0xFFFFFFFFu;
        else if (threadIdx.x < 32) umax[threadIdx.x - 16] = 0u;
    }
    if (blockIdx.x == 701 && threadIdx.x < 256) cs_fix[threadIdx.x] = 0ull;

    int w = blockIdx.x * (blockDim.x >> 6) + (threadIdx.x >> 6); // 0..3071
    int lane = threadIdx.x & 63;
    int mat = w >> 10, row = w & 1023;
    const float* W = (mat == 0) ? Wr : (mat == 1) ? Wk : Wv;
    const float4* Wrow = (const float4*)(W + (size_t)row * C);
    const float4* x4 = (const float4*)x;
    float acc = 0.f;
#pragma unroll
    for (int i = 0; i < 4; ++i) {
        float4 a = Wrow[i * 64 + lane];
        float4 b = x4[i * 64 + lane];
        acc += a.x * b.x + a.y * b.y + a.z * b.z + a.w * b.w;
    }
#pragma unroll
    for (int off = 32; off; off >>= 1) acc += __shfl_xor(acc, off);
    if (lane == 0) { (mat == 0 ? q : (mat == 1 ? kn : vn))[row] = acc; }
}

// ------- K2: per-head raw scores s[h][t] = qh.k_cache[t,h]  (+minmax) --------
__global__ void k_scores(const float* __restrict__ kc, const float* __restrict__ q,
                         float* __restrict__ s, unsigned* __restrict__ umin,
                         unsigned* __restrict__ umax) {
    __shared__ float smn[4][16], smx[4][16];
    int wid = blockIdx.x * (blockDim.x >> 6) + (threadIdx.x >> 6);
    int lane = threadIdx.x & 63, wave = threadIdx.x >> 6;
    int nw = gridDim.x * (blockDim.x >> 6);
    const float4* q4 = (const float4*)q;
    float4 qv[4];
#pragma unroll
    for (int i = 0; i < 4; ++i) qv[i] = q4[i * 64 + lane];
    float mnv[4] = {3.4e38f, 3.4e38f, 3.4e38f, 3.4e38f};
    float mxv[4] = {-3.4e38f, -3.4e38f, -3.4e38f, -3.4e38f};
    for (int t = wid; t < CT; t += nw) {
        const float4* row = (const float4*)(kc + (size_t)t * C);
        float acc[4];
#pragma unroll
        for (int i = 0; i < 4; ++i) {
            float4 a = row[i * 64 + lane];
            acc[i] = a.x * qv[i].x + a.y * qv[i].y + a.z * qv[i].z + a.w * qv[i].w;
        }
#pragma unroll
        for (int off = 8; off; off >>= 1) {
#pragma unroll
            for (int i = 0; i < 4; ++i) acc[i] += __shfl_xor(acc[i], off);
        }
        if ((lane & 15) == 0) {
            int g = lane >> 4;
#pragma unroll
            for (int i = 0; i < 4; ++i) {
                s[(size_t)(4 * i + g) * CT + t] = acc[i];
                if (t < PAST) {
                    mnv[i] = fminf(mnv[i], acc[i]);
                    mxv[i] = fmaxf(mxv[i], acc[i]);
                }
            }
        }
    }
    if ((lane & 15) == 0) {
        int g = lane >> 4;
#pragma unroll
        for (int i = 0; i < 4; ++i) { smn[wave][4 * i + g] = mnv[i]; smx[wave][4 * i + g] = mxv[i]; }
    }
    __syncthreads();
    if (threadIdx.x < 16) {
        int h = threadIdx.x;
        float mn = smn[0][h], mx = smx[0][h];
        for (int w2 = 1; w2 < 4; ++w2) {
            mn = fminf(mn, smn[w2][h]);
            mx = fmaxf(mx, smx[w2][h]);
        }
        atomicMin(&umin[h], desc_key(mx));   // smallest key == largest value
        atomicMax(&umax[h], desc_key(mn));   // largest key == smallest value
    }
}

// ---------------- S1: linear-bin histogram over PAST (4 blocks/head) ---------
__global__ __launch_bounds__(1024) void s1_hist(const float* __restrict__ s,
                                                unsigned* __restrict__ hist,
                                                const unsigned* __restrict__ umin,
                                                const unsigned* __restrict__ umax) {
    __shared__ unsigned lh[NB];
    int h = blockIdx.x >> 2, seg = blockIdx.x & 3;
    int tid = threadIdx.x;
    for (int i = tid; i < NB; i += 1024) lh[i] = 0;
    __syncthreads();
    float hi, sc; load_params(umin, umax, h, &hi, &sc);
    const float* sh = s + (size_t)h * CT + seg * 15360;
    for (int i = tid; i < 15360; i += 1024)
        atomicAdd(&lh[bin_of(sh[i], hi, sc)], 1u);
    __syncthreads();
    unsigned* gh = hist + h * NB;
    for (int i = tid; i < NB; i += 1024) {
        unsigned c = lh[i];
        if (c) atomicAdd(&gh[i], c);
    }
}

// ------- S2: distributed exclusive scan + threshold bin T (1 block/head) -----
__global__ __launch_bounds__(1024) void s2_scan(unsigned* __restrict__ base,
                                                unsigned* __restrict__ Tarr) {
    __shared__ unsigned wsum[16];
    int h = blockIdx.x, tid = threadIdx.x, lane = tid & 63, wave = tid >> 6;
    unsigned* B = base + h * NB;
    unsigned cnt[8];
    unsigned loc = 0;
    int b0 = tid * 8;
#pragma unroll
    for (int k = 0; k < 8; ++k) { cnt[k] = B[b0 + k]; loc += cnt[k]; }
    unsigned run = loc;
#pragma unroll
    for (int off = 1; off < 64; off <<= 1) {
        unsigned n = __shfl_up(run, off);
        if (lane >= off) run += n;
    }
    if (lane == 63) wsum[wave] = run;
    __syncthreads();
    if (wave == 0 && lane < 16) {
        unsigned v = wsum[lane];
#pragma unroll
        for (int off = 1; off < 16; off <<= 1) {
            unsigned n = __shfl_up(v, off);
            if (lane >= off) v += n;
        }
        wsum[lane] = v;
    }
    __syncthreads();
    unsigned r = run - loc + (wave ? wsum[wave - 1] : 0u);
#pragma unroll
    for (int k = 0; k < 8; ++k) {
        unsigned c = cnt[k];
        B[b0 + k] = r;               // own bins only: no cross-thread hazard
        unsigned inc = r + c;
        if (r < KEEP && inc >= KEEP) Tarr[h] = (unsigned)(b0 + k);
        r = inc;
    }
}

// ---- S3: scatter candidates (bins <= T) into G; +16 window-sum blocks -------
__global__ __launch_bounds__(1024) void s3_scatter(const float* __restrict__ s,
                                                   unsigned* __restrict__ base,
                                                   const unsigned* __restrict__ Tarr,
                                                   ull* __restrict__ G,
                                                   const unsigned* __restrict__ umin,
                                                   const unsigned* __restrict__ umax,
                                                   ull* __restrict__ cs_fix) {
    if (blockIdx.x >= 960) {                 // window-chunk fixed-point sums
        int h = blockIdx.x - 960;
        int tid = threadIdx.x;
        int c = tid >> 4;                    // 16 threads per chunk
        const float* sh = s + (size_t)h * CT + PAST + tid * 4;
        long long f = llrintf(sh[0] * 16777216.f) + llrintf(sh[1] * 16777216.f)
                    + llrintf(sh[2] * 16777216.f) + llrintf(sh[3] * 16777216.f);
#pragma unroll
        for (int off = 8; off; off >>= 1) f += __shfl_xor(f, off);
        if ((tid & 15) == 0) atomicAdd(&cs_fix[NCOMP + c], (ull)f);
        return;
    }
    int h = blockIdx.x / 60, seg = blockIdx.x % 60;
    int t = seg * 1024 + threadIdx.x;   // < 61440
    float hi, sc; load_params(umin, umax, h, &hi, &sc);
    float v = s[(size_t)h * CT + t];
    int b = bin_of(v, hi, sc);
    if ((unsigned)b <= Tarr[h]) {
        unsigned pos = atomicAdd(&base[h * NB + b], 1u);
        G[(size_t)h * 65536 + pos] = ((ull)desc_key(v) << 16) | (unsigned)t;
    }
}

// ---- S4: exact rank; emit stok + chunk sums; last block: top-32 -------------
__global__ __launch_bounds__(1024) void s4_rank(const unsigned* __restrict__ base,
                                                const unsigned* __restrict__ Tarr,
                                                const ull* __restrict__ G,
                                                const unsigned* __restrict__ umin,
                                                const unsigned* __restrict__ umax,
                                                unsigned short* __restrict__ stok,
                                                ull* __restrict__ cs_fix,
                                                unsigned* __restrict__ sel,
                                                unsigned* __restrict__ bar) {
    __shared__ ull csl[NCOMP];
    __shared__ unsigned sh_last;
    __shared__ ull key[256];
    const int tid = threadIdx.x;
    {
        if (tid < NCOMP) csl[tid] = 0ull;
        __syncthreads();
        int h = blockIdx.x >> 4, seg = blockIdx.x & 15;
        float hi, sc; load_params(umin, umax, h, &hi, &sc);
        unsigned T = Tarr[h];
        unsigned ncand = base[h * NB + T];
        const ull* Gh = G + (size_t)h * 65536;
        for (unsigned p = seg * 1024 + tid; p < ncand; p += 16384) {
            ull pk = Gh[p];
            unsigned u = (unsigned)(pk >> 16);
            float v = u_to_f(u);
            int b = bin_of(v, hi, sc);
            unsigned start = b ? base[h * NB + b - 1] : 0u;
            unsigned end = base[h * NB + b];
            unsigned rank = start;
            for (unsigned j = start; j < end; ++j) rank += (Gh[j] < pk) ? 1u : 0u;
            if (rank < KEEP) {
                stok[h * KEEP + rank] = (unsigned short)(pk & 0xFFFFull);
                long long f = llrintf(v * 16777216.f);
                atomicAdd(&csl[rank >> 6], (ull)f);
            }
        }
        __syncthreads();
        if (tid < NCOMP) {
            ull c = csl[tid];
            if (c) atomicAdd(&cs_fix[tid], c);
        }
    }
    // arrival; last block computes top-32 (parallel bitonic in LDS)
    __syncthreads();
    if (tid == 0) sh_last = (atomicAdd(&bar[1], 1u) == 255u) ? 1u : 0u;
    __syncthreads();
    if (!sh_last) return;
    __threadfence();                         // acquire (single block only)
    __syncthreads();
    if (tid < 256) {
        long long v = (long long)cs_fix[tid];
        ull bb = (ull)(v + (1ll << 45));                       // strictly positive
        key[tid] = (((1ull << 46) - bb) << 8) | (unsigned)tid; // asc == (val desc, idx asc)
    }
    __syncthreads();
    for (unsigned k = 2; k <= 256; k <<= 1) {
        for (unsigned j = k >> 1; j > 0; j >>= 1) {
            if (tid < 256) {
                unsigned ixj = tid ^ j;
                if (ixj > (unsigned)tid) {
                    ull a = key[tid], b = key[ixj];
                    bool up = ((tid & k) == 0);
                    if (up ? (a > b) : (a < b)) { key[tid] = b; key[ixj] = a; }
                }
            }
            __syncthreads();
        }
    }
    if (tid < NSEL) sel[tid] = (unsigned)(key[tid] & 0xFFull);
}

// ---------------- K5a: per (head, selected chunk) partial softmax+PV ---------
__global__ void k_attn_part(const float* __restrict__ s, const float* __restrict__ vc,
                            const unsigned short* __restrict__ stok,
                            const unsigned int* __restrict__ sel,
                            float* __restrict__ part) {
    int h = blockIdx.x >> 5, ci = blockIdx.x & 31;
    int tid = threadIdx.x;     // 256
    int g = tid >> 2, b3 = tid & 3;
    int c = (int)sel[ci];
    int t = (c < NCOMP) ? (int)stok[h * KEEP + c * 64 + g]
                        : (PAST + (c - NCOMP) * 64 + g);
    __shared__ float scm[64];
    __shared__ float ex[64];
    __shared__ float vbuf[64][65];
    if (b3 == 0) scm[g] = s[(size_t)h * CT + t] * 0.125f;
    __syncthreads();
    float m = -1e30f;
    for (int j = 0; j < 64; ++j) m = fmaxf(m, scm[j]);
    float e = expf(scm[g] - m);
    const float4* vrow = (const float4*)(vc + (size_t)t * C + h * HS);
#pragma unroll
    for (int it = 0; it < 4; ++it) {
        float4 vv = vrow[it * 4 + b3];
        int d0 = it * 16 + b3 * 4;
        vbuf[g][d0 + 0] = e * vv.x;
        vbuf[g][d0 + 1] = e * vv.y;
        vbuf[g][d0 + 2] = e * vv.z;
        vbuf[g][d0 + 3] = e * vv.w;
    }
    if (b3 == 0) ex[g] = e;
    __syncthreads();
    if (tid < 64) {
        float acc = 0.f;
        for (int g2 = 0; g2 < 64; ++g2) acc += vbuf[g2][tid];
        float* P = part + (size_t)(h * 32 + ci) * 68;
        P[2 + tid] = acc;
        if (tid == 0) {
            float es = 0.f;
            for (int g2 = 0; g2 < 64; ++g2) es += ex[g2];
            P[0] = m;
            P[1] = es;
        }
    }
}

// ------- K6: combine partials -> y (LDS, redundant per block) -> out ---------
__global__ __launch_bounds__(1024) void k_finout(const float* __restrict__ part,
        const float* __restrict__ q, const float* __restrict__ kn,
        const float* __restrict__ vn, const float* __restrict__ Wo,
        float* __restrict__ out) {
    __shared__ float yl[1024];
    __shared__ float qdl[16];
    const int tid = threadIdx.x, wave = tid >> 6, lane = tid & 63;
    {
        float p = q[wave * 64 + lane] * kn[wave * 64 + lane];
#pragma unroll
        for (int off = 32; off; off >>= 1) p += __shfl_xor(p, off);
        if (lane == 0) qdl[wave] = p;
    }
    __syncthreads();
    {
        float a_new = qdl[wave] * 0.125f;
        const float* P0 = part + (size_t)wave * 32 * 68;
        float m = a_new;
        for (int ci = 0; ci < 32; ++ci) m = fmaxf(m, P0[ci * 68]);
        float den = expf(a_new - m);
        float acc = den * vn[wave * HS + lane];
        for (int ci = 0; ci < 32; ++ci) {
            float w = expf(P0[ci * 68] - m);
            den += w * P0[ci * 68 + 1];
            acc += w * P0[ci * 68 + 2 + lane];
        }
        yl[tid] = acc / den;
    }
    __syncthreads();
    int r = blockIdx.x * 16 + wave;            // 0..1023
    const float4* Wrow = (const float4*)(Wo + (size_t)r * C);
    const float4* y4 = (const float4*)yl;
    float acc = 0.f;
#pragma unroll
    for (int i = 0; i < 4; ++i) {
        float4 a = Wrow[i * 64 + lane];
        float4 b = y4[i * 64 + lane];
        acc += a.x * b.x + a.y * b.y + a.z * b.z + a.w * b.w;
    }
#pragma unroll
    for (int off = 32; off; off >>= 1) acc += __shfl_xor(acc, off);
    if (lane == 0) out[r] = acc;
}

extern "C" void kernel_launch(void* const* d_in, const int* in_sizes, int n_in,
                              void* d_out, int out_size, void* d_ws, size_t ws_size,
                              hipStream_t stream) {
    const float* x  = (const float*)d_in[0];
    const float* kc = (const float*)d_in[1];
    const float* vc = (const float*)d_in[2];
    const float* Wr = (const float*)d_in[3];
    const float* Wk = (const float*)d_in[4];
    const float* Wv = (const float*)d_in[5];
    const float* Wo = (const float*)d_in[6];
    float* out = (float*)d_out;
    char* ws = (char*)d_ws;

    float* q    = (float*)(ws + 0);
    float* kn   = (float*)(ws + 8192);
    float* vn   = (float*)(ws + 16384);
    ull* cs_fix = (ull*)(ws + 32768);                         // 2 KiB
    unsigned* sel = (unsigned*)(ws + 40960);
    float* part = (float*)(ws + 49152);                       // 139264 B
    unsigned short* stok = (unsigned short*)(ws + 196608);    // 393216 B
    unsigned* umin = (unsigned*)(ws + 602112);
    unsigned* umax = (unsigned*)(ws + 602176);
    unsigned* Tarr = (unsigned*)(ws + 602240);
    unsigned* bar  = (unsigned*)(ws + 602368);                // 8 counters
    unsigned* base = (unsigned*)(ws + 655360);                // 512 KiB
    float* s = (float*)(ws + 2097152);                        // 4 MiB
    ull* G = (ull*)(ws + 6291456);                            // 8 MiB

    k_proj<<<768, 256, 0, stream>>>(x, Wr, Wk, Wv, q, kn, vn, base, umin, umax, cs_fix, bar);
    k_scores<<<2048, 256, 0, stream>>>(kc, q, s, umin, umax);
    s1_hist<<<64, 1024, 0, stream>>>(s, base, umin, umax);
    s2_scan<<<16, 1024, 0, stream>>>(base, Tarr);
    s3_scatter<<<976, 1024, 0, stream>>>(s, base, Tarr, G, umin, umax, cs_fix);
    s4_rank<<<256, 1024, 0, stream>>>(base, Tarr, G, umin, umax, stok, cs_fix, sel, bar);
    k_attn_part<<<512, 256, 0, stream>>>(s, vc, stok, sel, part);
    k_finout<<<64, 1024, 0, stream>>>(part, q, kn, vn, Wo, out);
}

// Round 9
// 143.464 us; speedup vs baseline: 3.1874x; 1.0143x over previous
//
#include <hip/hip_runtime.h>
#include <stdint.h>

#define C      1024
#define NH     16
#define HS     64
#define CT     65536
#define PAST   61440   // CT - WINDOW
#define KEEP   12288   // MIN_KV - WINDOW
#define NCOMP  192     // KEEP/64
#define NSEL   32
#define NB     8192    // selection bins

typedef unsigned long long ull;

// monotone transform: larger float => smaller u (asc u == desc value)
__device__ __forceinline__ unsigned int desc_key(float f) {
    unsigned int b = __float_as_uint(f);
    return (b >> 31) ? b : (~b & 0x7FFFFFFFu);
}
__device__ __forceinline__ float u_to_f(unsigned int u) {
    unsigned int b = (u & 0x80000000u) ? u : (0x7FFFFFFFu - u);
    return __uint_as_float(b);
}
// monotone linear bin: s descending <-> bin ascending
__device__ __forceinline__ int bin_of(float s, float hi, float scale) {
    int b = (int)((hi - s) * scale);
    return b < 0 ? 0 : (b > NB - 1 ? NB - 1 : b);
}
__device__ __forceinline__ void load_params(const unsigned* umin, const unsigned* umax,
                                            int h, float* hi, float* sc) {
    float h2 = u_to_f(umin[h]);
    float lo = u_to_f(umax[h]);
    float r = h2 - lo;
    *hi = h2;
    *sc = (r > 0.f) ? (float)(NB - 1) / r : 0.f;
}

// ---------------- K1: q/k/v projections + all zero-inits ---------------------
__global__ void k_proj(const float* __restrict__ x, const float* __restrict__ Wr,
                       const float* __restrict__ Wk, const float* __restrict__ Wv,
                       float* __restrict__ q, float* __restrict__ kn, float* __restrict__ vn,
                       unsigned* __restrict__ hist, unsigned* __restrict__ umin,
                       unsigned* __restrict__ umax, ull* __restrict__ cs_fix,
                       unsigned* __restrict__ bar) {
    int id = blockIdx.x * 256 + threadIdx.x;
    if (id < NH * NB) hist[id] = 0;
    if (blockIdx.x == 699 && threadIdx.x < 8) bar[threadIdx.x] = 0u;
    if (blockIdx.x == 700) {
        if (threadIdx.x < 16) umin[threadIdx.x] = 0xFFFFFFFFu;
        else if (threadIdx.x < 32) umax[threadIdx.x - 16] = 0u;
    }
    if (blockIdx.x == 701 && threadIdx.x < 256) cs_fix[threadIdx.x] = 0ull;

    int w = blockIdx.x * (blockDim.x >> 6) + (threadIdx.x >> 6); // 0..3071
    int lane = threadIdx.x & 63;
    int mat = w >> 10, row = w & 1023;
    const float* W = (mat == 0) ? Wr : (mat == 1) ? Wk : Wv;
    const float4* Wrow = (const float4*)(W + (size_t)row * C);
    const float4* x4 = (const float4*)x;
    float acc = 0.f;
#pragma unroll
    for (int i = 0; i < 4; ++i) {
        float4 a = Wrow[i * 64 + lane];
        float4 b = x4[i * 64 + lane];
        acc += a.x * b.x + a.y * b.y + a.z * b.z + a.w * b.w;
    }
#pragma unroll
    for (int off = 32; off; off >>= 1) acc += __shfl_xor(acc, off);
    if (lane == 0) { (mat == 0 ? q : (mat == 1 ? kn : vn))[row] = acc; }
}

// ------- K2: per-head raw scores (+minmax); XCD-swizzled blocks --------------
__global__ void k_scores(const float* __restrict__ kc, const float* __restrict__ q,
                         float* __restrict__ s, unsigned* __restrict__ umin,
                         unsigned* __restrict__ umax) {
    __shared__ float smn[4][16], smx[4][16];
    int b = blockIdx.x;
    int vb = ((b & 7) << 8) | (b >> 3);        // bijective for 2048 blocks
    int lane = threadIdx.x & 63, wave = threadIdx.x >> 6;
    int wid = vb * 4 + wave;                   // 0..8191
    int nw = 8192;
    const float4* q4 = (const float4*)q;
    float4 qv[4];
#pragma unroll
    for (int i = 0; i < 4; ++i) qv[i] = q4[i * 64 + lane];
    float mnv[4] = {3.4e38f, 3.4e38f, 3.4e38f, 3.4e38f};
    float mxv[4] = {-3.4e38f, -3.4e38f, -3.4e38f, -3.4e38f};
    for (int t = wid; t < CT; t += nw) {
        const float4* row = (const float4*)(kc + (size_t)t * C);
        float acc[4];
#pragma unroll
        for (int i = 0; i < 4; ++i) {
            float4 a = row[i * 64 + lane];
            acc[i] = a.x * qv[i].x + a.y * qv[i].y + a.z * qv[i].z + a.w * qv[i].w;
        }
#pragma unroll
        for (int off = 8; off; off >>= 1) {
#pragma unroll
            for (int i = 0; i < 4; ++i) acc[i] += __shfl_xor(acc[i], off);
        }
        if ((lane & 15) == 0) {
            int g = lane >> 4;
#pragma unroll
            for (int i = 0; i < 4; ++i) {
                s[(size_t)(4 * i + g) * CT + t] = acc[i];
                if (t < PAST) {
                    mnv[i] = fminf(mnv[i], acc[i]);
                    mxv[i] = fmaxf(mxv[i], acc[i]);
                }
            }
        }
    }
    if ((lane & 15) == 0) {
        int g = lane >> 4;
#pragma unroll
        for (int i = 0; i < 4; ++i) { smn[wave][4 * i + g] = mnv[i]; smx[wave][4 * i + g] = mxv[i]; }
    }
    __syncthreads();
    if (threadIdx.x < 16) {
        int h = threadIdx.x;
        float mn = smn[0][h], mx = smx[0][h];
        for (int w2 = 1; w2 < 4; ++w2) {
            mn = fminf(mn, smn[w2][h]);
            mx = fmaxf(mx, smx[w2][h]);
        }
        atomicMin(&umin[h], desc_key(mx));   // smallest key == largest value
        atomicMax(&umax[h], desc_key(mn));   // largest key == smallest value
    }
}

// ---------------- S1: linear-bin histogram over PAST (16 blocks/head) --------
__global__ __launch_bounds__(1024) void s1_hist(const float* __restrict__ s,
                                                unsigned* __restrict__ hist,
                                                const unsigned* __restrict__ umin,
                                                const unsigned* __restrict__ umax) {
    __shared__ unsigned lh[NB];
    int h = blockIdx.x >> 4, seg = blockIdx.x & 15;
    int tid = threadIdx.x;
    for (int i = tid; i < NB; i += 1024) lh[i] = 0;
    __syncthreads();
    float hi, sc; load_params(umin, umax, h, &hi, &sc);
    const float* sh = s + (size_t)h * CT + seg * 3840;
    for (int i = tid; i < 3840; i += 1024)
        atomicAdd(&lh[bin_of(sh[i], hi, sc)], 1u);
    __syncthreads();
    unsigned* gh = hist + h * NB;
    for (int i = tid; i < NB; i += 1024) {
        unsigned c = lh[i];
        if (c) atomicAdd(&gh[i], c);
    }
}

// ------- S2a: per-(head, 512-bin segment) sums -------------------------------
__global__ __launch_bounds__(256) void s2a_sum(const unsigned* __restrict__ base,
                                               unsigned* __restrict__ gsum) {
    __shared__ unsigned wred[4];
    int h = blockIdx.x >> 4, seg = blockIdx.x & 15;
    int tid = threadIdx.x, lane = tid & 63, wave = tid >> 6;
    const unsigned* B = base + h * NB + seg * 512;
    unsigned sm = B[tid] + B[tid + 256];
#pragma unroll
    for (int off = 32; off; off >>= 1) sm += __shfl_xor(sm, off);
    if (lane == 0) wred[wave] = sm;
    __syncthreads();
    if (tid == 0) gsum[blockIdx.x] = wred[0] + wred[1] + wred[2] + wred[3];
}

// ------- S2b: tiny scan of 16 segments per head (1 block) --------------------
__global__ __launch_bounds__(256) void s2b_scan(const unsigned* __restrict__ gsum,
                                                unsigned* __restrict__ gexc) {
    int tid = threadIdx.x;          // h = tid>>4, seg = tid&15; lane&15 == seg
    int lane = tid & 63;
    unsigned v = gsum[tid];
    unsigned incl = v;
#pragma unroll
    for (int off = 1; off < 16; off <<= 1) {
        unsigned n = __shfl_up(incl, off);
        if ((lane & 15) >= off) incl += n;
    }
    gexc[tid] = incl - v;
}

// ------- S2c: write exclusive bases + threshold bin T ------------------------
__global__ __launch_bounds__(512) void s2c_base(unsigned* __restrict__ base,
                                                const unsigned* __restrict__ gexc,
                                                unsigned* __restrict__ Tarr) {
    __shared__ unsigned wsum[8];
    int h = blockIdx.x >> 4, seg = blockIdx.x & 15;
    int tid = threadIdx.x, lane = tid & 63, wave = tid >> 6;
    unsigned* B = base + h * NB + seg * 512;
    unsigned c = B[tid];
    unsigned incl = c;
#pragma unroll
    for (int off = 1; off < 64; off <<= 1) {
        unsigned n = __shfl_up(incl, off);
        if (lane >= off) incl += n;
    }
    if (lane == 63) wsum[wave] = incl;
    __syncthreads();
    if (wave == 0 && lane < 8) {
        unsigned v = wsum[lane];
#pragma unroll
        for (int off = 1; off < 8; off <<= 1) {
            unsigned n = __shfl_up(v, off);
            if (lane >= off) v += n;
        }
        wsum[lane] = v;
    }
    __syncthreads();
    unsigned excl = incl - c + (wave ? wsum[wave - 1] : 0u) + gexc[h * 16 + seg];
    B[tid] = excl;
    if (excl < KEEP && excl + c >= KEEP) Tarr[h] = (unsigned)(seg * 512 + tid);
}

// ---- S3: scatter candidates (bins <= T) into G; +16 window-sum blocks -------
__global__ __launch_bounds__(1024) void s3_scatter(const float* __restrict__ s,
                                                   unsigned* __restrict__ base,
                                                   const unsigned* __restrict__ Tarr,
                                                   ull* __restrict__ G,
                                                   const unsigned* __restrict__ umin,
                                                   const unsigned* __restrict__ umax,
                                                   ull* __restrict__ cs_fix) {
    if (blockIdx.x >= 960) {                 // window-chunk fixed-point sums
        int h = blockIdx.x - 960;
        int tid = threadIdx.x;
        int c = tid >> 4;                    // 16 threads per chunk
        const float* sh = s + (size_t)h * CT + PAST + tid * 4;
        long long f = llrintf(sh[0] * 16777216.f) + llrintf(sh[1] * 16777216.f)
                    + llrintf(sh[2] * 16777216.f) + llrintf(sh[3] * 16777216.f);
#pragma unroll
        for (int off = 8; off; off >>= 1) f += __shfl_xor(f, off);
        if ((tid & 15) == 0) atomicAdd(&cs_fix[NCOMP + c], (ull)f);
        return;
    }
    int h = blockIdx.x / 60, seg = blockIdx.x % 60;
    int t = seg * 1024 + threadIdx.x;   // < 61440
    float hi, sc; load_params(umin, umax, h, &hi, &sc);
    float v = s[(size_t)h * CT + t];
    int b = bin_of(v, hi, sc);
    if ((unsigned)b <= Tarr[h]) {
        unsigned pos = atomicAdd(&base[h * NB + b], 1u);
        G[(size_t)h * 65536 + pos] = ((ull)desc_key(v) << 16) | (unsigned)t;
    }
}

// ---- S4: exact rank; emit stok + chunk sums; last block: top-32 -------------
__global__ __launch_bounds__(1024) void s4_rank(const unsigned* __restrict__ base,
                                                const unsigned* __restrict__ Tarr,
                                                const ull* __restrict__ G,
                                                const unsigned* __restrict__ umin,
                                                const unsigned* __restrict__ umax,
                                                unsigned short* __restrict__ stok,
                                                ull* __restrict__ cs_fix,
                                                unsigned* __restrict__ sel,
                                                unsigned* __restrict__ bar) {
    __shared__ ull csl[NCOMP];
    __shared__ unsigned sh_last;
    __shared__ ull key[256];
    const int tid = threadIdx.x;
    {
        if (tid < NCOMP) csl[tid] = 0ull;
        __syncthreads();
        int h = blockIdx.x >> 4, seg = blockIdx.x & 15;
        float hi, sc; load_params(umin, umax, h, &hi, &sc);
        unsigned T = Tarr[h];
        unsigned ncand = base[h * NB + T];
        const ull* Gh = G + (size_t)h * 65536;
        for (unsigned p = seg * 1024 + tid; p < ncand; p += 16384) {
            ull pk = Gh[p];
            unsigned u = (unsigned)(pk >> 16);
            float v = u_to_f(u);
            int b = bin_of(v, hi, sc);
            unsigned start = b ? base[h * NB + b - 1] : 0u;
            unsigned end = base[h * NB + b];
            unsigned rank = start;
            for (unsigned j = start; j < end; ++j) rank += (Gh[j] < pk) ? 1u : 0u;
            if (rank < KEEP) {
                stok[h * KEEP + rank] = (unsigned short)(pk & 0xFFFFull);
                long long f = llrintf(v * 16777216.f);
                atomicAdd(&csl[rank >> 6], (ull)f);
            }
        }
        __syncthreads();
        if (tid < NCOMP) {
            ull c = csl[tid];
            if (c) atomicAdd(&cs_fix[tid], c);
        }
    }
    // arrival; last block computes top-32 (parallel bitonic in LDS)
    __syncthreads();
    if (tid == 0) sh_last = (atomicAdd(&bar[1], 1u) == 255u) ? 1u : 0u;
    __syncthreads();
    if (!sh_last) return;
    __threadfence();                         // acquire (single block only)
    __syncthreads();
    if (tid < 256) {
        long long v = (long long)cs_fix[tid];
        ull bb = (ull)(v + (1ll << 45));                       // strictly positive
        key[tid] = (((1ull << 46) - bb) << 8) | (unsigned)tid; // asc == (val desc, idx asc)
    }
    __syncthreads();
    for (unsigned k = 2; k <= 256; k <<= 1) {
        for (unsigned j = k >> 1; j > 0; j >>= 1) {
            if (tid < 256) {
                unsigned ixj = tid ^ j;
                if (ixj > (unsigned)tid) {
                    ull a = key[tid], b = key[ixj];
                    bool up = ((tid & k) == 0);
                    if (up ? (a > b) : (a < b)) { key[tid] = b; key[ixj] = a; }
                }
            }
            __syncthreads();
        }
    }
    if (tid < NSEL) sel[tid] = (unsigned)(key[tid] & 0xFFull);
}

// ---------------- K5a: per (head, selected chunk) partial softmax+PV ---------
__global__ void k_attn_part(const float* __restrict__ s, const float* __restrict__ vc,
                            const unsigned short* __restrict__ stok,
                            const unsigned int* __restrict__ sel,
                            float* __restrict__ part) {
    int h = blockIdx.x >> 5, ci = blockIdx.x & 31;
    int tid = threadIdx.x;     // 256
    int g = tid >> 2, b3 = tid & 3;
    int c = (int)sel[ci];
    int t = (c < NCOMP) ? (int)stok[h * KEEP + c * 64 + g]
                        : (PAST + (c - NCOMP) * 64 + g);
    __shared__ float scm[64];
    __shared__ float ex[64];
    __shared__ float vbuf[64][65];
    if (b3 == 0) scm[g] = s[(size_t)h * CT + t] * 0.125f;
    __syncthreads();
    float m = -1e30f;
    for (int j = 0; j < 64; ++j) m = fmaxf(m, scm[j]);
    float e = expf(scm[g] - m);
    const float4* vrow = (const float4*)(vc + (size_t)t * C + h * HS);
#pragma unroll
    for (int it = 0; it < 4; ++it) {
        float4 vv = vrow[it * 4 + b3];
        int d0 = it * 16 + b3 * 4;
        vbuf[g][d0 + 0] = e * vv.x;
        vbuf[g][d0 + 1] = e * vv.y;
        vbuf[g][d0 + 2] = e * vv.z;
        vbuf[g][d0 + 3] = e * vv.w;
    }
    if (b3 == 0) ex[g] = e;
    __syncthreads();
    if (tid < 64) {
        float acc = 0.f;
        for (int g2 = 0; g2 < 64; ++g2) acc += vbuf[g2][tid];
        float* P = part + (size_t)(h * 32 + ci) * 68;
        P[2 + tid] = acc;
        if (tid == 0) {
            float es = 0.f;
            for (int g2 = 0; g2 < 64; ++g2) es += ex[g2];
            P[0] = m;
            P[1] = es;
        }
    }
}

// ------- K6: combine partials -> y (LDS, redundant per block) -> out ---------
__global__ __launch_bounds__(1024) void k_finout(const float* __restrict__ part,
        const float* __restrict__ q, const float* __restrict__ kn,
        const float* __restrict__ vn, const float* __restrict__ Wo,
        float* __restrict__ out) {
    __shared__ float yl[1024];
    __shared__ float qdl[16];
    const int tid = threadIdx.x, wave = tid >> 6, lane = tid & 63;
    {
        float p = q[wave * 64 + lane] * kn[wave * 64 + lane];
#pragma unroll
        for (int off = 32; off; off >>= 1) p += __shfl_xor(p, off);
        if (lane == 0) qdl[wave] = p;
    }
    __syncthreads();
    {
        float a_new = qdl[wave] * 0.125f;
        const float* P0 = part + (size_t)wave * 32 * 68;
        float m = a_new;
        for (int ci = 0; ci < 32; ++ci) m = fmaxf(m, P0[ci * 68]);
        float den = expf(a_new - m);
        float acc = den * vn[wave * HS + lane];
        for (int ci = 0; ci < 32; ++ci) {
            float w = expf(P0[ci * 68] - m);
            den += w * P0[ci * 68 + 1];
            acc += w * P0[ci * 68 + 2 + lane];
        }
        yl[tid] = acc / den;
    }
    __syncthreads();
    int r = blockIdx.x * 16 + wave;            // 0..1023
    const float4* Wrow = (const float4*)(Wo + (size_t)r * C);
    const float4* y4 = (const float4*)yl;
    float acc = 0.f;
#pragma unroll
    for (int i = 0; i < 4; ++i) {
        float4 a = Wrow[i * 64 + lane];
        float4 b = y4[i * 64 + lane];
        acc += a.x * b.x + a.y * b.y + a.z * b.z + a.w * b.w;
    }
#pragma unroll
    for (int off = 32; off; off >>= 1) acc += __shfl_xor(acc, off);
    if (lane == 0) out[r] = acc;
}

extern "C" void kernel_launch(void* const* d_in, const int* in_sizes, int n_in,
                              void* d_out, int out_size, void* d_ws, size_t ws_size,
                              hipStream_t stream) {
    const float* x  = (const float*)d_in[0];
    const float* kc = (const float*)d_in[1];
    const float* vc = (const float*)d_in[2];
    const float* Wr = (const float*)d_in[3];
    const float* Wk = (const float*)d_in[4];
    const float* Wv = (const float*)d_in[5];
    const float* Wo = (const float*)d_in[6];
    float* out = (float*)d_out;
    char* ws = (char*)d_ws;

    float* q    = (float*)(ws + 0);
    float* kn   = (float*)(ws + 8192);
    float* vn   = (float*)(ws + 16384);
    ull* cs_fix = (ull*)(ws + 32768);                         // 2 KiB
    unsigned* sel = (unsigned*)(ws + 40960);
    float* part = (float*)(ws + 49152);                       // 139264 B
    unsigned short* stok = (unsigned short*)(ws + 196608);    // 393216 B
    unsigned* umin = (unsigned*)(ws + 602112);
    unsigned* umax = (unsigned*)(ws + 602176);
    unsigned* Tarr = (unsigned*)(ws + 602240);
    unsigned* bar  = (unsigned*)(ws + 602368);                // 8 counters
    unsigned* gsum = (unsigned*)(ws + 602432);                // 1 KiB
    unsigned* gexc = (unsigned*)(ws + 603456);                // 1 KiB
    unsigned* base = (unsigned*)(ws + 655360);                // 512 KiB
    float* s = (float*)(ws + 2097152);                        // 4 MiB
    ull* G = (ull*)(ws + 6291456);                            // 8 MiB

    k_proj<<<768, 256, 0, stream>>>(x, Wr, Wk, Wv, q, kn, vn, base, umin, umax, cs_fix, bar);
    k_scores<<<2048, 256, 0, stream>>>(kc, q, s, umin, umax);
    s1_hist<<<256, 1024, 0, stream>>>(s, base, umin, umax);
    s2a_sum<<<256, 256, 0, stream>>>(base, gsum);
    s2b_scan<<<1, 256, 0, stream>>>(gsum, gexc);
    s2c_base<<<256, 512, 0, stream>>>(base, gexc, Tarr);
    s3_scatter<<<976, 1024, 0, stream>>>(s, base, Tarr, G, umin, umax, cs_fix);
    s4_rank<<<256, 1024, 0, stream>>>(base, Tarr, G, umin, umax, stok, cs_fix, sel, bar);
    k_attn_part<<<512, 256, 0, stream>>>(s, vc, stok, sel, part);
    k_finout<<<64, 1024, 0, stream>>>(part, q, kn, vn, Wo, out);
}